// Round 1
// baseline (356.853 us; speedup 1.0000x reference)
//
#include <hip/hip_runtime.h>
#include <math.h>

#define N_RAYS   32768
#define N_SAMP   1048576
#define HID      64

// ---------------------------------------------------------------------------
// Pass A: per-sample MLPs. One thread = one sample.
// Weights are wave-uniform loads -> scalar cache; only acc[64] lives in VGPRs.
// Writes float4 {rgb.x, rgb.y, rgb.z, sigma_dt} per sample into workspace.
// ---------------------------------------------------------------------------
__global__ __launch_bounds__(256) void pass_a(
    const float* __restrict__ rays_o, const float* __restrict__ rays_d,
    const float* __restrict__ t_starts, const float* __restrict__ t_ends,
    const int*   __restrict__ ray_idx,
    const float* __restrict__ Wd1, const float* __restrict__ bd1,
    const float* __restrict__ Wd2, const float* __restrict__ bd2,
    const float* __restrict__ Wd3, const float* __restrict__ bd3,
    const float* __restrict__ Wr1, const float* __restrict__ br1,
    const float* __restrict__ Wr2, const float* __restrict__ br2,
    const float* __restrict__ Wr3, const float* __restrict__ br3,
    float4* __restrict__ ws4)
{
    int s = blockIdx.x * blockDim.x + threadIdx.x;
    if (s >= N_SAMP) return;

    int   r   = ray_idx[s];
    float ts  = t_starts[s], te = t_ends[s];
    float mid = 0.5f * (ts + te);
    float dt  = te - ts;

    float px = rays_o[r*3+0] + rays_d[r*3+0] * mid;
    float py = rays_o[r*3+1] + rays_d[r*3+1] * mid;
    float pz = rays_o[r*3+2] + rays_d[r*3+2] * mid;

    float acc[HID];

    // ---- density MLP: 3 -> 64 -> 64 -> 1, softplus ----
    #pragma unroll
    for (int j = 0; j < HID; ++j) acc[j] = bd2[j];
    for (int k = 0; k < HID; ++k) {
        float h = fmaxf(px*Wd1[k] + py*Wd1[HID+k] + pz*Wd1[2*HID+k] + bd1[k], 0.f);
        #pragma unroll
        for (int j = 0; j < HID; ++j) acc[j] += h * Wd2[k*HID + j];
    }
    float sig = bd3[0];
    #pragma unroll
    for (int j = 0; j < HID; ++j) sig += fmaxf(acc[j], 0.f) * Wd3[j];
    // stable softplus: max(x,0) + log1p(exp(-|x|))
    float sp = fmaxf(sig, 0.f) + log1pf(expf(-fabsf(sig)));
    float sigma_dt = sp * dt;

    // ---- rgb MLP: 3 -> 64 -> 64 -> 3, sigmoid ----
    #pragma unroll
    for (int j = 0; j < HID; ++j) acc[j] = br2[j];
    for (int k = 0; k < HID; ++k) {
        float h = fmaxf(px*Wr1[k] + py*Wr1[HID+k] + pz*Wr1[2*HID+k] + br1[k], 0.f);
        #pragma unroll
        for (int j = 0; j < HID; ++j) acc[j] += h * Wr2[k*HID + j];
    }
    float o0 = br3[0], o1 = br3[1], o2 = br3[2];
    #pragma unroll
    for (int j = 0; j < HID; ++j) {
        float h = fmaxf(acc[j], 0.f);
        o0 += h * Wr3[j*3 + 0];
        o1 += h * Wr3[j*3 + 1];
        o2 += h * Wr3[j*3 + 2];
    }
    o0 = 1.f / (1.f + expf(-o0));
    o1 = 1.f / (1.f + expf(-o1));
    o2 = 1.f / (1.f + expf(-o2));

    ws4[s] = make_float4(o0, o1, o2, sigma_dt);
}

// ---------------------------------------------------------------------------
// Pass B: per-ray accumulation. One thread = one ray.
// ray_indices is sorted -> each ray's samples are a contiguous range found by
// binary search. Sequential exclusive cumsum of sigma_dt within the ray.
// ---------------------------------------------------------------------------
__global__ __launch_bounds__(256) void pass_b(
    const float* __restrict__ t_starts, const float* __restrict__ t_ends,
    const int*   __restrict__ ray_idx,
    const float4* __restrict__ ws4,
    float* __restrict__ out)
{
    int r = blockIdx.x * blockDim.x + threadIdx.x;
    if (r >= N_RAYS) return;

    // lower_bound(ray_idx, r)
    int lo = 0, hi = N_SAMP;
    while (lo < hi) { int m = (lo + hi) >> 1; if (ray_idx[m] < r) lo = m + 1; else hi = m; }
    int s0 = lo;
    // lower_bound(ray_idx, r+1), search space [s0, N_SAMP)
    hi = N_SAMP;
    while (lo < hi) { int m = (lo + hi) >> 1; if (ray_idx[m] < r + 1) lo = m + 1; else hi = m; }
    int s1 = lo;

    float cum = 0.f, opac = 0.f, dist = 0.f;
    float c0 = 0.f, c1 = 0.f, c2 = 0.f;
    for (int s = s0; s < s1; ++s) {
        float4 v  = ws4[s];
        float sd  = v.w;
        float mid = 0.5f * (t_starts[s] + t_ends[s]);
        float trans = expf(-cum);
        float alpha = -expm1f(-sd);        // 1 - exp(-sd), accurately
        float w = trans * alpha;
        opac += w;
        dist += w * mid;
        c0 += w * v.x; c1 += w * v.y; c2 += w * v.z;
        cum += sd;
    }

    float rest = 1.f - opac;
    out[r*3 + 0] = c0 + 0.5f * rest;
    out[r*3 + 1] = c1 + 0.5f * rest;
    out[r*3 + 2] = c2 + 0.5f * rest;
    out[3*N_RAYS + r] = dist + 5.f * rest;   // distances
    out[4*N_RAYS + r] = opac;                // opacities
}

extern "C" void kernel_launch(void* const* d_in, const int* in_sizes, int n_in,
                              void* d_out, int out_size, void* d_ws, size_t ws_size,
                              hipStream_t stream) {
    const float* rays_o   = (const float*)d_in[0];
    const float* rays_d   = (const float*)d_in[1];
    const float* t_starts = (const float*)d_in[2];
    const float* t_ends   = (const float*)d_in[3];
    const int*   ray_idx  = (const int*)  d_in[4];
    const float* Wd1 = (const float*)d_in[5];  const float* bd1 = (const float*)d_in[6];
    const float* Wd2 = (const float*)d_in[7];  const float* bd2 = (const float*)d_in[8];
    const float* Wd3 = (const float*)d_in[9];  const float* bd3 = (const float*)d_in[10];
    const float* Wr1 = (const float*)d_in[11]; const float* br1 = (const float*)d_in[12];
    const float* Wr2 = (const float*)d_in[13]; const float* br2 = (const float*)d_in[14];
    const float* Wr3 = (const float*)d_in[15]; const float* br3 = (const float*)d_in[16];

    float4* ws4 = (float4*)d_ws;              // 16 MB: {rgb, sigma_dt} per sample
    float*  out = (float*)d_out;

    dim3 blkA(256), grdA((N_SAMP + 255) / 256);
    hipLaunchKernelGGL(pass_a, grdA, blkA, 0, stream,
                       rays_o, rays_d, t_starts, t_ends, ray_idx,
                       Wd1, bd1, Wd2, bd2, Wd3, bd3,
                       Wr1, br1, Wr2, br2, Wr3, br3, ws4);

    dim3 blkB(256), grdB((N_RAYS + 255) / 256);
    hipLaunchKernelGGL(pass_b, grdB, blkB, 0, stream,
                       t_starts, t_ends, ray_idx, ws4, out);
}

// Round 2
// 184.625 us; speedup vs baseline: 1.9329x; 1.9329x over previous
//
#include <hip/hip_runtime.h>
#include <hip/hip_bf16.h>
#include <math.h>

#define N_RAYS   32768
#define N_SAMP   1048576
#define HID      64
#define TPW      16          // 16-sample tiles per wave
#define BLK_A    1024        // 1024 blk * 4 waves * TPW * 16 = 1,048,576 samples

typedef short bf8 __attribute__((ext_vector_type(8)));   // 8 x bf16 bits
typedef float f4  __attribute__((ext_vector_type(4)));

static __device__ __forceinline__ short f2bf(float x) {
  union { __bf16 h; short s; } u;
  u.h = (__bf16)x;            // RNE f32->bf16
  return u.s;
}

static __device__ __forceinline__ f4 mfma16(bf8 a, bf8 b, f4 c) {
  return __builtin_amdgcn_mfma_f32_16x16x32_bf16(a, b, c, 0, 0, 0);
}

// ---------------------------------------------------------------------------
// Pass A: fully-register-resident transposed MFMA MLP chain.
// D = W^T @ X^T orientation keeps col=lane&15 == sample down the whole chain.
// Weight A-frags use permuted rows pi(t,q,r) = 8q + 4(t&1) + r + 32(t>>1) so
// that D-tile registers ARE the next layer's B-frag elements (relu+pack only).
// ---------------------------------------------------------------------------
__global__ __launch_bounds__(256, 2) void pass_a(
    const float* __restrict__ rays_o, const float* __restrict__ rays_d,
    const float* __restrict__ t_starts, const float* __restrict__ t_ends,
    const int*   __restrict__ ray_idx,
    const float* __restrict__ Wd1, const float* __restrict__ bd1,
    const float* __restrict__ Wd2, const float* __restrict__ bd2,
    const float* __restrict__ Wd3, const float* __restrict__ bd3,
    const float* __restrict__ Wr1, const float* __restrict__ br1,
    const float* __restrict__ Wr2, const float* __restrict__ br2,
    const float* __restrict__ Wr3, const float* __restrict__ br3,
    float4* __restrict__ ws4)
{
    const int lane = threadIdx.x & 63;
    const int wv   = (blockIdx.x * blockDim.x + threadIdx.x) >> 6;  // global wave
    const int q    = lane >> 4;      // quad
    const int n    = lane & 15;      // column index == sample-in-tile
    const int qn   = n >> 2, rn = n & 3;

    // ---- constant fragments (loop-invariant, live in VGPRs) ----
    bf8 a1d[4], a1r[4];
    #pragma unroll
    for (int t = 0; t < 4; ++t) {
        int row = 8*qn + 4*(t&1) + rn + 32*(t>>1);
        bf8 fd, fr;
        #pragma unroll
        for (int j = 0; j < 8; ++j) { fd[j] = 0; fr[j] = 0; }
        if (q == 0) {
            #pragma unroll
            for (int j = 0; j < 3; ++j) {
                fd[j] = f2bf(Wd1[j*HID + row]);
                fr[j] = f2bf(Wr1[j*HID + row]);
            }
            fd[3] = f2bf(bd1[row]);
            fr[3] = f2bf(br1[row]);
        }
        a1d[t] = fd; a1r[t] = fr;
    }

    bf8 a2d[4][2], a2r[4][2];
    #pragma unroll
    for (int t = 0; t < 4; ++t) {
        int row = 8*qn + 4*(t&1) + rn + 32*(t>>1);
        #pragma unroll
        for (int s = 0; s < 2; ++s) {
            bf8 fd, fr;
            #pragma unroll
            for (int j = 0; j < 8; ++j) {
                int k = 8*q + j + 32*s;
                fd[j] = f2bf(Wd2[k*HID + row]);
                fr[j] = f2bf(Wr2[k*HID + row]);
            }
            a2d[t][s] = fd; a2r[t][s] = fr;
        }
    }

    bf8 a3[4];
    #pragma unroll
    for (int s = 0; s < 4; ++s) {
        bf8 f;
        #pragma unroll
        for (int j = 0; j < 8; ++j) {
            int kg = 32*s + 8*q + j;
            float v = 0.f;
            if (n == 0 && s < 2)                 v = Wd3[kg];
            else if (n >= 1 && n <= 3 && s >= 2) v = Wr3[(kg-64)*3 + (n-1)];
            f[j] = f2bf(v);
        }
        a3[s] = f;
    }

    f4 bias2d[4], bias2r[4];
    #pragma unroll
    for (int t = 0; t < 4; ++t) {
        #pragma unroll
        for (int rr = 0; rr < 4; ++rr) {
            int row = 8*q + 4*(t&1) + rr + 32*(t>>1);
            bias2d[t][rr] = bd2[row];
            bias2r[t][rr] = br2[row];
        }
    }
    f4 bias3;
    #pragma unroll
    for (int rr = 0; rr < 4; ++rr)
        bias3[rr] = (q == 0) ? (rr == 0 ? bd3[0] : br3[rr-1]) : 0.f;

    const int base0 = wv * (TPW * 16);

    #pragma unroll 1
    for (int tt = 0; tt < TPW; ++tt) {
        const int smp = base0 + tt*16 + n;
        float ts = t_starts[smp], te = t_ends[smp];
        int   ri = ray_idx[smp];
        float mid = 0.5f*(ts+te), dt = te - ts;
        float px = rays_o[3*ri+0] + rays_d[3*ri+0]*mid;
        float py = rays_o[3*ri+1] + rays_d[3*ri+1]*mid;
        float pz = rays_o[3*ri+2] + rays_d[3*ri+2]*mid;

        bf8 xb;
        #pragma unroll
        for (int j = 0; j < 8; ++j) xb[j] = 0;
        if (q == 0) {
            xb[0] = f2bf(px); xb[1] = f2bf(py);
            xb[2] = f2bf(pz); xb[3] = f2bf(1.0f);
        }

        f4 zero = {0.f, 0.f, 0.f, 0.f};

        f4 d1d[4], d1r[4];
        #pragma unroll
        for (int t = 0; t < 4; ++t) {
            d1d[t] = mfma16(a1d[t], xb, zero);
            d1r[t] = mfma16(a1r[t], xb, zero);
        }

        bf8 b2d[2], b2r[2];
        #pragma unroll
        for (int s = 0; s < 2; ++s) {
            #pragma unroll
            for (int j = 0; j < 8; ++j) {
                b2d[s][j] = f2bf(fmaxf(d1d[2*s + (j>>2)][j&3], 0.f));
                b2r[s][j] = f2bf(fmaxf(d1r[2*s + (j>>2)][j&3], 0.f));
            }
        }

        f4 d2d[4], d2r[4];
        #pragma unroll
        for (int t = 0; t < 4; ++t) {
            f4 ad = bias2d[t];
            ad = mfma16(a2d[t][0], b2d[0], ad);
            ad = mfma16(a2d[t][1], b2d[1], ad);
            d2d[t] = ad;
            f4 ar = bias2r[t];
            ar = mfma16(a2r[t][0], b2r[0], ar);
            ar = mfma16(a2r[t][1], b2r[1], ar);
            d2r[t] = ar;
        }

        bf8 b3[4];
        #pragma unroll
        for (int s = 0; s < 2; ++s) {
            #pragma unroll
            for (int j = 0; j < 8; ++j) {
                b3[s][j]   = f2bf(fmaxf(d2d[2*s + (j>>2)][j&3], 0.f));
                b3[s+2][j] = f2bf(fmaxf(d2r[2*s + (j>>2)][j&3], 0.f));
            }
        }

        f4 c3 = bias3;
        #pragma unroll
        for (int s = 0; s < 4; ++s) c3 = mfma16(a3[s], b3[s], c3);

        if (q == 0) {
            float sg = c3[0];
            float sp = fmaxf(sg, 0.f) + log1pf(expf(-fabsf(sg)));
            float sd = sp * dt;
            float r0 = 1.f/(1.f + expf(-c3[1]));
            float g0 = 1.f/(1.f + expf(-c3[2]));
            float b0 = 1.f/(1.f + expf(-c3[3]));
            ws4[smp] = make_float4(r0, g0, b0, sd);
        }
    }
}

__global__ __launch_bounds__(256) void seg_starts(
    const int* __restrict__ ray_idx, int* __restrict__ start)
{
    int s = blockIdx.x * blockDim.x + threadIdx.x;
    if (s >= N_SAMP) return;
    int b = ray_idx[s];
    int a = (s == 0) ? -1 : ray_idx[s-1];
    for (int r = a + 1; r <= b; ++r) start[r] = s;
    if (s == N_SAMP - 1)
        for (int r = b + 1; r <= N_RAYS; ++r) start[r] = N_SAMP;
}

__global__ __launch_bounds__(256) void pass_b(
    const float* __restrict__ t_starts, const float* __restrict__ t_ends,
    const float4* __restrict__ ws4, const int* __restrict__ start,
    float* __restrict__ out)
{
    const int lane = threadIdx.x & 63;
    const int r    = (blockIdx.x * blockDim.x + threadIdx.x) >> 6;
    if (r >= N_RAYS) return;

    const int s0 = start[r], s1 = start[r+1];

    float cum = 0.f, opac = 0.f, dist = 0.f, c0 = 0.f, c1 = 0.f, c2 = 0.f;

    for (int base = s0; base < s1; base += 64) {
        int s = base + lane;
        bool ok = s < s1;
        float4 v = ok ? ws4[s] : make_float4(0.f, 0.f, 0.f, 0.f);
        float mid = ok ? 0.5f*(t_starts[s] + t_ends[s]) : 0.f;
        float sd = v.w;

        float x = sd;
        #pragma unroll
        for (int off = 1; off < 64; off <<= 1) {
            float y = __shfl_up(x, off, 64);
            if (lane >= off) x += y;
        }
        float excl  = x - sd;
        float trans = expf(-(cum + excl));
        float w     = trans * (-expm1f(-sd));
        opac += w; dist += w*mid;
        c0 += w*v.x; c1 += w*v.y; c2 += w*v.z;
        cum += __shfl(x, 63, 64);
    }

    #pragma unroll
    for (int off = 32; off > 0; off >>= 1) {
        opac += __shfl_xor(opac, off, 64);
        dist += __shfl_xor(dist, off, 64);
        c0   += __shfl_xor(c0,   off, 64);
        c1   += __shfl_xor(c1,   off, 64);
        c2   += __shfl_xor(c2,   off, 64);
    }

    if (lane == 0) {
        float rest = 1.f - opac;
        out[r*3 + 0] = c0 + 0.5f * rest;
        out[r*3 + 1] = c1 + 0.5f * rest;
        out[r*3 + 2] = c2 + 0.5f * rest;
        out[3*N_RAYS + r] = dist + 5.f * rest;
        out[4*N_RAYS + r] = opac;
    }
}

extern "C" void kernel_launch(void* const* d_in, const int* in_sizes, int n_in,
                              void* d_out, int out_size, void* d_ws, size_t ws_size,
                              hipStream_t stream) {
    const float* rays_o   = (const float*)d_in[0];
    const float* rays_d   = (const float*)d_in[1];
    const float* t_starts = (const float*)d_in[2];
    const float* t_ends   = (const float*)d_in[3];
    const int*   ray_idx  = (const int*)  d_in[4];
    const float* Wd1 = (const float*)d_in[5];  const float* bd1 = (const float*)d_in[6];
    const float* Wd2 = (const float*)d_in[7];  const float* bd2 = (const float*)d_in[8];
    const float* Wd3 = (const float*)d_in[9];  const float* bd3 = (const float*)d_in[10];
    const float* Wr1 = (const float*)d_in[11]; const float* br1 = (const float*)d_in[12];
    const float* Wr2 = (const float*)d_in[13]; const float* br2 = (const float*)d_in[14];
    const float* Wr3 = (const float*)d_in[15]; const float* br3 = (const float*)d_in[16];

    float4* ws4   = (float4*)d_ws;                                // 16 MB
    int*    start = (int*)((char*)d_ws + (size_t)N_SAMP * 16);    // +128 KB
    float*  out   = (float*)d_out;

    hipLaunchKernelGGL(pass_a, dim3(BLK_A), dim3(256), 0, stream,
                       rays_o, rays_d, t_starts, t_ends, ray_idx,
                       Wd1, bd1, Wd2, bd2, Wd3, bd3,
                       Wr1, br1, Wr2, br2, Wr3, br3, ws4);

    hipLaunchKernelGGL(seg_starts, dim3((N_SAMP + 255)/256), dim3(256), 0, stream,
                       ray_idx, start);

    hipLaunchKernelGGL(pass_b, dim3((N_RAYS*64)/256), dim3(256), 0, stream,
                       t_starts, t_ends, ws4, start, out);
}

// Round 3
// 163.945 us; speedup vs baseline: 2.1767x; 1.1261x over previous
//
#include <hip/hip_runtime.h>
#include <hip/hip_bf16.h>
#include <math.h>

#define N_RAYS   32768
#define N_SAMP   1048576
#define HID      64
#define ITERS    4
#define BLK_A    1024   // 1024 blk * 4 waves * ITERS * 64 = 1,048,576 samples

typedef short bf8 __attribute__((ext_vector_type(8)));   // 8 x bf16 bits
typedef float f4  __attribute__((ext_vector_type(4)));

union BF8U { bf8 v; unsigned u[4]; };

static __device__ __forceinline__ unsigned bfbits(float x) {
    union { __bf16 h; unsigned short s; } c; c.h = (__bf16)x; return (unsigned)c.s;
}
static __device__ __forceinline__ unsigned pk2(float a, float b) {
    return bfbits(a) | (bfbits(b) << 16);
}
static __device__ __forceinline__ unsigned pk2r(float a, float b) {
    return pk2(fmaxf(a, 0.f), fmaxf(b, 0.f));
}
static __device__ __forceinline__ f4 mfma16(bf8 a, bf8 b, f4 c) {
    return __builtin_amdgcn_mfma_f32_16x16x32_bf16(a, b, c, 0, 0, 0);
}

// ---------------------------------------------------------------------------
// Pass A: 64 samples per wave-iteration, 4 16-col MFMA tiles.
// Tile-select trick: W1 rows replicated into EVERY quad's k-slots of A1;
// tile u's B1 is nonzero only in quad u -> each lane feeds its OWN sample
// (coalesced loads, no shuffles, no redundancy). Chain handoff is pure
// in-lane relu + dword-pair bf16 pack (pi-permuted weight rows).
// Also emits segment starts (boundary detect via shfl) -> start[].
// ---------------------------------------------------------------------------
__global__ __launch_bounds__(256, 2) void pass_a(
    const float* __restrict__ rays_o, const float* __restrict__ rays_d,
    const float* __restrict__ t_starts, const float* __restrict__ t_ends,
    const int*   __restrict__ ray_idx,
    const float* __restrict__ Wd1, const float* __restrict__ bd1,
    const float* __restrict__ Wd2, const float* __restrict__ bd2,
    const float* __restrict__ Wd3, const float* __restrict__ bd3,
    const float* __restrict__ Wr1, const float* __restrict__ br1,
    const float* __restrict__ Wr2, const float* __restrict__ br2,
    const float* __restrict__ Wr3, const float* __restrict__ br3,
    float4* __restrict__ ws4, int* __restrict__ start)
{
    const int lane = threadIdx.x & 63;
    const int wv   = (blockIdx.x * blockDim.x + threadIdx.x) >> 6;
    const int q    = lane >> 4;
    const int n    = lane & 15;
    const int qn   = n >> 2, rn = n & 3;

    // ---- A1: rows pi(t,n); W1 j-rows + bias replicated in all quads ----
    bf8 a1d[4], a1r[4];
    #pragma unroll
    for (int t = 0; t < 4; ++t) {
        const int row = 8*qn + 4*(t&1) + rn + 32*(t>>1);
        BF8U fd, fr;
        fd.u[0] = pk2(Wd1[row],       Wd1[HID+row]);
        fd.u[1] = pk2(Wd1[2*HID+row], bd1[row]);
        fd.u[2] = 0u; fd.u[3] = 0u;
        fr.u[0] = pk2(Wr1[row],       Wr1[HID+row]);
        fr.u[1] = pk2(Wr1[2*HID+row], br1[row]);
        fr.u[2] = 0u; fr.u[3] = 0u;
        a1d[t] = fd.v; a1r[t] = fr.v;
    }

    // ---- A2: rows pi(t,n), k = 8q + j + 32s ----
    bf8 a2d[4][2], a2r[4][2];
    #pragma unroll
    for (int t = 0; t < 4; ++t) {
        const int row = 8*qn + 4*(t&1) + rn + 32*(t>>1);
        #pragma unroll
        for (int s = 0; s < 2; ++s) {
            BF8U fd, fr;
            #pragma unroll
            for (int dw = 0; dw < 4; ++dw) {
                const int k = 8*q + 2*dw + 32*s;
                fd.u[dw] = pk2(Wd2[k*HID+row], Wd2[(k+1)*HID+row]);
                fr.u[dw] = pk2(Wr2[k*HID+row], Wr2[(k+1)*HID+row]);
            }
            a2d[t][s] = fd.v; a2r[t][s] = fr.v;
        }
    }

    // ---- A3: row0 = Wd3 (k<64), rows1..3 = Wr3 (k>=64) ----
    bf8 a3[4];
    #pragma unroll
    for (int s = 0; s < 4; ++s) {
        BF8U f;
        #pragma unroll
        for (int dw = 0; dw < 4; ++dw) {
            const int kg = 32*s + 8*q + 2*dw;
            float va = 0.f, vb = 0.f;
            if (n == 0 && s < 2)                 { va = Wd3[kg]; vb = Wd3[kg+1]; }
            else if (n >= 1 && n <= 3 && s >= 2) {
                va = Wr3[(kg-64)*3 + (n-1)];
                vb = Wr3[(kg-63)*3 + (n-1)];
            }
            f.u[dw] = pk2(va, vb);
        }
        a3[s] = f.v;
    }

    // ---- accumulator biases ----
    f4 bias2d[4], bias2r[4];
    #pragma unroll
    for (int t = 0; t < 4; ++t) {
        #pragma unroll
        for (int rr = 0; rr < 4; ++rr) {
            const int row = 8*q + 4*(t&1) + rr + 32*(t>>1);
            bias2d[t][rr] = bd2[row];
            bias2r[t][rr] = br2[row];
        }
    }
    f4 bias3;
    #pragma unroll
    for (int rr = 0; rr < 4; ++rr)
        bias3[rr] = (q == 0) ? (rr == 0 ? bd3[0] : br3[rr-1]) : 0.f;

    const int base0 = wv * (ITERS * 64);

    #pragma unroll 1
    for (int it = 0; it < ITERS; ++it) {
        const int base = base0 + it * 64;
        const int smp  = base + lane;

        const float ts = t_starts[smp], te = t_ends[smp];
        const int   ri = ray_idx[smp];
        const float mid = 0.5f*(ts+te), dt = te - ts;
        const float px = rays_o[3*ri+0] + rays_d[3*ri+0]*mid;
        const float py = rays_o[3*ri+1] + rays_d[3*ri+1]*mid;
        const float pz = rays_o[3*ri+2] + rays_d[3*ri+2]*mid;
        const unsigned p01 = pk2(px, py);
        const unsigned p23 = pk2(pz, 1.0f);

        // segment boundaries (replaces seg_starts kernel)
        int rp = __shfl_up(ri, 1, 64);
        if (lane == 0) rp = (smp == 0) ? -1 : ray_idx[smp-1];
        for (int rr = rp + 1; rr <= ri; ++rr) start[rr] = smp;
        if (smp == N_SAMP - 1)
            for (int rr = ri + 1; rr <= N_RAYS; ++rr) start[rr] = N_SAMP;

        #pragma unroll
        for (int u = 0; u < 4; ++u) {
            BF8U xb;
            xb.u[0] = (q == u) ? p01 : 0u;
            xb.u[1] = (q == u) ? p23 : 0u;
            xb.u[2] = 0u; xb.u[3] = 0u;

            const f4 zero = {0.f, 0.f, 0.f, 0.f};
            f4 d1d[4], d1r[4];
            #pragma unroll
            for (int t = 0; t < 4; ++t) {
                d1d[t] = mfma16(a1d[t], xb.v, zero);
                d1r[t] = mfma16(a1r[t], xb.v, zero);
            }

            bf8 b2d[2], b2r[2];
            #pragma unroll
            for (int s = 0; s < 2; ++s) {
                BF8U pd, pr;
                pd.u[0] = pk2r(d1d[2*s][0],   d1d[2*s][1]);
                pd.u[1] = pk2r(d1d[2*s][2],   d1d[2*s][3]);
                pd.u[2] = pk2r(d1d[2*s+1][0], d1d[2*s+1][1]);
                pd.u[3] = pk2r(d1d[2*s+1][2], d1d[2*s+1][3]);
                pr.u[0] = pk2r(d1r[2*s][0],   d1r[2*s][1]);
                pr.u[1] = pk2r(d1r[2*s][2],   d1r[2*s][3]);
                pr.u[2] = pk2r(d1r[2*s+1][0], d1r[2*s+1][1]);
                pr.u[3] = pk2r(d1r[2*s+1][2], d1r[2*s+1][3]);
                b2d[s] = pd.v; b2r[s] = pr.v;
            }

            f4 d2d[4], d2r[4];
            #pragma unroll
            for (int t = 0; t < 4; ++t) {
                f4 ad = bias2d[t];
                ad = mfma16(a2d[t][0], b2d[0], ad);
                ad = mfma16(a2d[t][1], b2d[1], ad);
                d2d[t] = ad;
                f4 ar = bias2r[t];
                ar = mfma16(a2r[t][0], b2r[0], ar);
                ar = mfma16(a2r[t][1], b2r[1], ar);
                d2r[t] = ar;
            }

            bf8 b3[4];
            #pragma unroll
            for (int s = 0; s < 2; ++s) {
                BF8U pd, pr;
                pd.u[0] = pk2r(d2d[2*s][0],   d2d[2*s][1]);
                pd.u[1] = pk2r(d2d[2*s][2],   d2d[2*s][3]);
                pd.u[2] = pk2r(d2d[2*s+1][0], d2d[2*s+1][1]);
                pd.u[3] = pk2r(d2d[2*s+1][2], d2d[2*s+1][3]);
                pr.u[0] = pk2r(d2r[2*s][0],   d2r[2*s][1]);
                pr.u[1] = pk2r(d2r[2*s][2],   d2r[2*s][3]);
                pr.u[2] = pk2r(d2r[2*s+1][0], d2r[2*s+1][1]);
                pr.u[3] = pk2r(d2r[2*s+1][2], d2r[2*s+1][3]);
                b3[s] = pd.v; b3[s+2] = pr.v;
            }

            f4 c3 = bias3;
            #pragma unroll
            for (int s = 0; s < 4; ++s) c3 = mfma16(a3[s], b3[s], c3);

            const float dtu = __shfl(dt, 16*u + n, 64);   // dt of output sample
            if (q == 0) {
                const float sg = c3[0];
                const float sp = fmaxf(sg, 0.f) + __logf(1.f + __expf(-fabsf(sg)));
                const float sd = sp * dtu;
                const float r0 = __builtin_amdgcn_rcpf(1.f + __expf(-c3[1]));
                const float g0 = __builtin_amdgcn_rcpf(1.f + __expf(-c3[2]));
                const float b0 = __builtin_amdgcn_rcpf(1.f + __expf(-c3[3]));
                ws4[base + 16*u + n] = make_float4(r0, g0, b0, sd);
            }
        }
    }
}

// ---------------------------------------------------------------------------
// Pass B: one wave per ray; shfl scan for transmittance, butterfly reduce.
// ---------------------------------------------------------------------------
__global__ __launch_bounds__(256) void pass_b(
    const float* __restrict__ t_starts, const float* __restrict__ t_ends,
    const float4* __restrict__ ws4, const int* __restrict__ start,
    float* __restrict__ out)
{
    const int lane = threadIdx.x & 63;
    const int r    = (blockIdx.x * blockDim.x + threadIdx.x) >> 6;
    if (r >= N_RAYS) return;

    const int s0 = start[r], s1 = start[r+1];

    float cum = 0.f, opac = 0.f, dist = 0.f, c0 = 0.f, c1 = 0.f, c2 = 0.f;

    for (int base = s0; base < s1; base += 64) {
        int s = base + lane;
        bool ok = s < s1;
        float4 v = ok ? ws4[s] : make_float4(0.f, 0.f, 0.f, 0.f);
        float mid = ok ? 0.5f*(t_starts[s] + t_ends[s]) : 0.f;
        float sd = v.w;

        float x = sd;
        #pragma unroll
        for (int off = 1; off < 64; off <<= 1) {
            float y = __shfl_up(x, off, 64);
            if (lane >= off) x += y;
        }
        float excl  = x - sd;
        float trans = __expf(-(cum + excl));
        float w     = trans * (-expm1f(-sd));
        opac += w; dist += w*mid;
        c0 += w*v.x; c1 += w*v.y; c2 += w*v.z;
        cum += __shfl(x, 63, 64);
    }

    #pragma unroll
    for (int off = 32; off > 0; off >>= 1) {
        opac += __shfl_xor(opac, off, 64);
        dist += __shfl_xor(dist, off, 64);
        c0   += __shfl_xor(c0,   off, 64);
        c1   += __shfl_xor(c1,   off, 64);
        c2   += __shfl_xor(c2,   off, 64);
    }

    if (lane == 0) {
        float rest = 1.f - opac;
        out[r*3 + 0] = c0 + 0.5f * rest;
        out[r*3 + 1] = c1 + 0.5f * rest;
        out[r*3 + 2] = c2 + 0.5f * rest;
        out[3*N_RAYS + r] = dist + 5.f * rest;
        out[4*N_RAYS + r] = opac;
    }
}

extern "C" void kernel_launch(void* const* d_in, const int* in_sizes, int n_in,
                              void* d_out, int out_size, void* d_ws, size_t ws_size,
                              hipStream_t stream) {
    const float* rays_o   = (const float*)d_in[0];
    const float* rays_d   = (const float*)d_in[1];
    const float* t_starts = (const float*)d_in[2];
    const float* t_ends   = (const float*)d_in[3];
    const int*   ray_idx  = (const int*)  d_in[4];
    const float* Wd1 = (const float*)d_in[5];  const float* bd1 = (const float*)d_in[6];
    const float* Wd2 = (const float*)d_in[7];  const float* bd2 = (const float*)d_in[8];
    const float* Wd3 = (const float*)d_in[9];  const float* bd3 = (const float*)d_in[10];
    const float* Wr1 = (const float*)d_in[11]; const float* br1 = (const float*)d_in[12];
    const float* Wr2 = (const float*)d_in[13]; const float* br2 = (const float*)d_in[14];
    const float* Wr3 = (const float*)d_in[15]; const float* br3 = (const float*)d_in[16];

    float4* ws4   = (float4*)d_ws;                                // 16 MB
    int*    start = (int*)((char*)d_ws + (size_t)N_SAMP * 16);    // +~128 KB
    float*  out   = (float*)d_out;

    hipLaunchKernelGGL(pass_a, dim3(BLK_A), dim3(256), 0, stream,
                       rays_o, rays_d, t_starts, t_ends, ray_idx,
                       Wd1, bd1, Wd2, bd2, Wd3, bd3,
                       Wr1, br1, Wr2, br2, Wr3, br3, ws4, start);

    hipLaunchKernelGGL(pass_b, dim3((N_RAYS*64)/256), dim3(256), 0, stream,
                       t_starts, t_ends, ws4, start, out);
}